// Round 1
// 289.061 us; speedup vs baseline: 1.0825x; 1.0825x over previous
//
#include <hip/hip_runtime.h>
#include <stdint.h>

#define MDIM 4096
#define NDIM 4096
#define KDIM 4096

#define BM 256
#define BN 256
#define BK 64
#define NT (KDIM / BK)   // 64 K-tiles

typedef __attribute__((ext_vector_type(8))) __bf16 bf16x8;
typedef __attribute__((ext_vector_type(4))) float f32x4;
typedef __attribute__((ext_vector_type(8))) unsigned short ushort8_t;
typedef __attribute__((ext_vector_type(4))) unsigned short ushort4_t;

typedef const __attribute__((address_space(1))) void* gas_ptr;
typedef __attribute__((address_space(3))) void* las_ptr;

__device__ __forceinline__ void async_load16(const void* g, void* l) {
    // global -> LDS direct DMA, 16B/lane; LDS dest = wave-uniform base + lane*16
    __builtin_amdgcn_global_load_lds((gas_ptr)g, (las_ptr)l, 16, 0, 0);
}

__device__ __forceinline__ unsigned short f32_to_bf16_rne(float f) {
    union { float f; uint32_t u; } v; v.f = f;
    uint32_t u = v.u;
    return (unsigned short)((u + 0x7FFFu + ((u >> 16) & 1u)) >> 16);
}

__device__ __forceinline__ unsigned short sgn_bf16(float w) {
    // sign() in bf16: +1 / -1 / 0
    return (w > 0.f) ? 0x3F80u : ((w < 0.f) ? 0xBF80u : 0u);
}

// ---------------- fused prep kernel ----------------
// blocks [0, XBLKS): x fp32 -> bf16 (16B loads+stores, grid-stride)
// blocks [XBLKS, XBLKS+4096): W[k][n] fp32 -> sign -> bf16, transposed to WqT[n][k]
// W-path: register-only 4x4 micro-transpose. No LDS, no __syncthreads.
// 8B stores are scattered but each 128B output line is fully covered within the
// block -> L2 write-combines to full-line writebacks.

#define XBLKS 2048

__global__ void prep_kernel(const float* __restrict__ x, const float* __restrict__ W,
                            unsigned short* __restrict__ xbf, unsigned short* __restrict__ wqT) {
    if (blockIdx.x < XBLKS) {
        const int tot8 = MDIM * KDIM / 8;
        int t = blockIdx.x * 256 + threadIdx.x;
        const int stride = XBLKS * 256;
        for (int i = t; i < tot8; i += stride) {
            float4 v0 = ((const float4*)x)[2 * i];
            float4 v1 = ((const float4*)x)[2 * i + 1];
            ushort8_t o;
            o[0] = f32_to_bf16_rne(v0.x); o[1] = f32_to_bf16_rne(v0.y);
            o[2] = f32_to_bf16_rne(v0.z); o[3] = f32_to_bf16_rne(v0.w);
            o[4] = f32_to_bf16_rne(v1.x); o[5] = f32_to_bf16_rne(v1.y);
            o[6] = f32_to_bf16_rne(v1.z); o[7] = f32_to_bf16_rne(v1.w);
            ((ushort8_t*)xbf)[i] = o;
        }
    } else {
        const int wb = blockIdx.x - XBLKS;          // 64x64 (k x n) tile of W
        const int n0 = (wb & 63) * 64;
        const int k0 = (wb >> 6) * 64;
        const int t  = threadIdx.x;
        const int kq = (t >> 4) * 4;                // k micro-row base, 0..60
        const int nq = (t & 15) * 4;                // n micro-col base, 0..60
        const float* src = &W[(size_t)(k0 + kq) * NDIM + n0 + nq];
        float4 v0 = *(const float4*)(src);
        float4 v1 = *(const float4*)(src + NDIM);
        float4 v2 = *(const float4*)(src + 2 * NDIM);
        float4 v3 = *(const float4*)(src + 3 * NDIM);
        const float* f0 = (const float*)&v0;
        const float* f1 = (const float*)&v1;
        const float* f2 = (const float*)&v2;
        const float* f3 = (const float*)&v3;
#pragma unroll
        for (int j = 0; j < 4; ++j) {
            ushort4_t o;
            o[0] = sgn_bf16(f0[j]);                 // k = k0+kq+0
            o[1] = sgn_bf16(f1[j]);
            o[2] = sgn_bf16(f2[j]);
            o[3] = sgn_bf16(f3[j]);
            *(ushort4_t*)&wqT[(size_t)(n0 + nq + j) * KDIM + k0 + kq] = o;
        }
    }
}

// ---------------- bf16 MFMA GEMM: 256x256 tile, 8 waves, phase-split K-loop ------
// grid = 16x16 = 256 blocks = 1/CU. LDS = 2 dbuf x (A 32KB + B 32KB) = 128 KiB.
// Per K-tile (BK=64): 4 MFMA phases x 16 mfma_f32_16x16x32_bf16 per wave.
// Staging: global_load_lds w/ 16B width; LDS dest linear, global SOURCE pre-swizzled
// chunk c' = c ^ (row&7); ds_read applies same XOR -> bank-balanced ds_read_b128.
// Stages for tile t+1 front-loaded into phases 0-1; ONE raw vmcnt(0)+s_barrier per
// K-tile (loads have ~2.5 phases of MFMA cover; no per-phase drain).

__global__ __launch_bounds__(512, 2) void gemm_bf16_bt(
        const unsigned short* __restrict__ A,
        const unsigned short* __restrict__ Bt,
        const float* __restrict__ bias,
        float* __restrict__ C)
{
    __shared__ __align__(16) unsigned short lds[2][2][BM * BK];  // [buf][A/B][256*64]

    const int tid  = threadIdx.x;
    const int wave = tid >> 6;          // 0..7
    const int lane = tid & 63;
    const int wm = wave >> 2;           // 0..1  -> 128 rows each
    const int wn = wave & 3;            // 0..3  -> 64 cols each

    // XCD-bijective swizzle (nwg=256, 256%8==0): XCD x gets 32 consecutive tiles
    int bid = blockIdx.y * gridDim.x + blockIdx.x;
    bid = (bid & 7) * 32 + (bid >> 3);
    const int bm = (bid >> 4) * BM;
    const int bn = (bid & 15) * BN;

    // ---- staging addressing (pre-swizzled global source) ----
    // 8-row group g (0..31) occupies LDS bytes g*1024..+1023, linear.
    // lane l -> row_local = l>>3, slot = l&7; source chunk = slot ^ row_local.
    const int lrow = lane >> 3;
    const int lchk = (lane & 7) ^ lrow;
    const size_t aSrc = (size_t)(bm + lrow) * KDIM + lchk * 8;   // elements
    const size_t bSrc = (size_t)(bn + lrow) * KDIM + lchk * 8;
    const int g0 = wave * 4;            // this wave's 4 groups per operand

#define STAGE_A(BUF, TK, G) async_load16(A  + aSrc + (size_t)(G) * (8 * KDIM) + (TK), \
                                         &lds[BUF][0][(G) * 512])
#define STAGE_B(BUF, TK, G) async_load16(Bt + bSrc + (size_t)(G) * (8 * KDIM) + (TK), \
                                         &lds[BUF][1][(G) * 512])

    // ---- fragment read addressing (XOR-swizzled) ----
    // frag elem j: [row = base + (lane&15)][k = ksub*32 + (lane>>4)*8 + j]
    // byte = row*128 + ((ksub*4 + (lane>>4)) ^ (row&7))*16 ; row&7 == lane&7
    const int frow = lane & 15;
    const int rb  = frow * 128;
    const int cx0 = ((lane >> 4) ^ (lane & 7)) << 4;
    const int cx1 = cx0 ^ 64;           // ksub=1 flips chunk bit2 -> byte bit6

    const char* L = (const char*)lds;
    const char* aP00 = L +     0 + wm * 16384 + rb + cx0;   // buf0, ksub0
    const char* aP01 = L +     0 + wm * 16384 + rb + cx1;   // buf0, ksub1
    const char* aP10 = L + 65536 + wm * 16384 + rb + cx0;
    const char* aP11 = L + 65536 + wm * 16384 + rb + cx1;
    const char* bP00 = L + 32768 +         wn * 8192 + rb + cx0;
    const char* bP01 = L + 32768 +         wn * 8192 + rb + cx1;
    const char* bP10 = L + 98304 +         wn * 8192 + rb + cx0;
    const char* bP11 = L + 98304 +         wn * 8192 + rb + cx1;

    f32x4 acc[8][4] = {};
    bf16x8 af[4][2];     // current m-group (grp0 in ph0/1, grp1 in ph2/3)
    bf16x8 bfr[4][2];    // all 4 n-frags

#define MFMA16(MIB, NIB)                                                        \
    _Pragma("unroll")                                                           \
    for (int mi = 0; mi < 4; ++mi)                                              \
        _Pragma("unroll")                                                       \
        for (int ni = 0; ni < 2; ++ni)                                          \
            _Pragma("unroll")                                                   \
            for (int ks = 0; ks < 2; ++ks)                                      \
                acc[(MIB) + mi][(NIB) + ni] =                                   \
                    __builtin_amdgcn_mfma_f32_16x16x32_bf16(                    \
                        af[mi][ks], bfr[(NIB) + ni][ks],                        \
                        acc[(MIB) + mi][(NIB) + ni], 0, 0, 0);

    // ---- prologue: stage tile 0 into buf 0, drain, rendezvous ----
    STAGE_A(0, 0, g0 + 0); STAGE_A(0, 0, g0 + 1);
    STAGE_A(0, 0, g0 + 2); STAGE_A(0, 0, g0 + 3);
    STAGE_B(0, 0, g0 + 0); STAGE_B(0, 0, g0 + 1);
    STAGE_B(0, 0, g0 + 2); STAGE_B(0, 0, g0 + 3);
    asm volatile("s_waitcnt vmcnt(0)" ::: "memory");
    __builtin_amdgcn_s_barrier();
    asm volatile("" ::: "memory");
    __builtin_amdgcn_sched_barrier(0);

    for (int t = 0; t < NT; ++t) {
        const bool odd  = t & 1;
        const char* aK0 = odd ? aP10 : aP00;
        const char* aK1 = odd ? aP11 : aP01;
        const char* bK0 = odd ? bP10 : bP00;
        const char* bK1 = odd ? bP11 : bP01;
        const int  nxt  = odd ? 0 : 1;
        const int  tk   = (t + 1) * BK;          // element col offset of next tile
        const bool more = (t + 1 < NT);

        // ---------- phase 0: read af(grp0)+bfr(n0,n1); stage 4 A-loads ----------
#pragma unroll
        for (int mi = 0; mi < 4; ++mi) {
            af[mi][0] = *(const bf16x8*)(aK0 + mi * 2048);
            af[mi][1] = *(const bf16x8*)(aK1 + mi * 2048);
        }
#pragma unroll
        for (int ni = 0; ni < 2; ++ni) {
            bfr[ni][0] = *(const bf16x8*)(bK0 + ni * 2048);
            bfr[ni][1] = *(const bf16x8*)(bK1 + ni * 2048);
        }
        if (more) {
            STAGE_A(nxt, tk, g0 + 0); STAGE_A(nxt, tk, g0 + 1);
            STAGE_A(nxt, tk, g0 + 2); STAGE_A(nxt, tk, g0 + 3);
        }
        __builtin_amdgcn_s_barrier();
        __builtin_amdgcn_s_setprio(1);
        MFMA16(0, 0)
        __builtin_amdgcn_s_setprio(0);
        __builtin_amdgcn_s_barrier();

        // ---------- phase 1: read bfr(n2,n3); stage 4 B-loads ----------
#pragma unroll
        for (int ni = 2; ni < 4; ++ni) {
            bfr[ni][0] = *(const bf16x8*)(bK0 + ni * 2048);
            bfr[ni][1] = *(const bf16x8*)(bK1 + ni * 2048);
        }
        if (more) {
            STAGE_B(nxt, tk, g0 + 0); STAGE_B(nxt, tk, g0 + 1);
            STAGE_B(nxt, tk, g0 + 2); STAGE_B(nxt, tk, g0 + 3);
        }
        __builtin_amdgcn_s_barrier();
        __builtin_amdgcn_s_setprio(1);
        MFMA16(0, 2)
        __builtin_amdgcn_s_setprio(0);
        __builtin_amdgcn_s_barrier();

        // ---------- phase 2: read af(grp1) ----------
#pragma unroll
        for (int mi = 0; mi < 4; ++mi) {
            af[mi][0] = *(const bf16x8*)(aK0 + 8192 + mi * 2048);
            af[mi][1] = *(const bf16x8*)(aK1 + 8192 + mi * 2048);
        }
        __builtin_amdgcn_s_barrier();
        __builtin_amdgcn_s_setprio(1);
        MFMA16(4, 2)
        __builtin_amdgcn_s_setprio(0);
        __builtin_amdgcn_s_barrier();

        // ---------- phase 3: pure MFMA, then tile boundary ----------
        __builtin_amdgcn_s_setprio(1);
        MFMA16(4, 0)
        __builtin_amdgcn_s_setprio(0);
        // own t+1 loads were issued >= 2 phases ago; wait them, rendezvous, pin.
        asm volatile("s_waitcnt vmcnt(0)" ::: "memory");
        __builtin_amdgcn_s_barrier();
        asm volatile("" ::: "memory");
        __builtin_amdgcn_sched_barrier(0);
    }

    // ---- epilogue: C/D layout col=lane&15, row=(lane>>4)*4+reg (m89/m91) ----
#pragma unroll
    for (int ni = 0; ni < 4; ++ni) {
        int col = bn + wn * 64 + ni * 16 + frow;
        float bv = bias[col];
#pragma unroll
        for (int mig = 0; mig < 8; ++mig) {
            int row0 = bm + wm * 128 + mig * 16 + (lane >> 4) * 4;
#pragma unroll
            for (int r = 0; r < 4; ++r)
                C[(size_t)(row0 + r) * NDIM + col] = acc[mig][ni][r] + bv;
        }
    }
#undef STAGE_A
#undef STAGE_B
#undef MFMA16
}

// ---------------- fallback: fp32 vector GEMM (only if ws too small) ----------------

__global__ void fallback_gemm(const float* __restrict__ x, const float* __restrict__ W,
                              const float* __restrict__ b, float* __restrict__ out) {
    __shared__ float As[32][32];
    __shared__ float Bs[32][33];
    int tx = threadIdx.x, ty = threadIdx.y;
    int row = blockIdx.y * 32 + ty;
    int col = blockIdx.x * 32 + tx;
    float acc = 0.0f;
    for (int kt = 0; kt < KDIM; kt += 32) {
        As[ty][tx] = x[(size_t)row * KDIM + kt + tx];
        float w = W[(size_t)(kt + ty) * NDIM + col];
        Bs[ty][tx] = (w > 0.0f) ? 1.0f : ((w < 0.0f) ? -1.0f : 0.0f);
        __syncthreads();
#pragma unroll
        for (int k = 0; k < 32; ++k) acc += As[ty][k] * Bs[k][tx];
        __syncthreads();
    }
    out[(size_t)row * NDIM + col] = acc + b[col];
}

// ---------------- launcher ----------------

extern "C" void kernel_launch(void* const* d_in, const int* in_sizes, int n_in,
                              void* d_out, int out_size, void* d_ws, size_t ws_size,
                              hipStream_t stream) {
    const float* x = (const float*)d_in[0];
    const float* W = (const float*)d_in[1];
    const float* b = (const float*)d_in[2];
    float* out = (float*)d_out;

    const size_t need = (size_t)MDIM * KDIM * 2 + (size_t)KDIM * NDIM * 2;  // 64 MB
    if (ws_size >= need) {
        unsigned short* xbf = (unsigned short*)d_ws;
        unsigned short* wqT = xbf + (size_t)MDIM * KDIM;

        prep_kernel<<<XBLKS + (NDIM / 64) * (KDIM / 64), 256, 0, stream>>>(x, W, xbf, wqT);
        gemm_bf16_bt<<<dim3(NDIM / BN, MDIM / BM), 512, 0, stream>>>(xbf, wqT, b, out);
    } else {
        fallback_gemm<<<dim3(NDIM / 32, MDIM / 32), dim3(32, 32), 0, stream>>>(x, W, b, out);
    }
}